// Round 1
// baseline (2585.858 us; speedup 1.0000x reference)
//
#include <hip/hip_runtime.h>

// Problem constants (derived from in_sizes at launch as well)
//   NE = 200000 edges, D = 64, H = 128
//   size-5 cycles: 30000 cycles x 5 rows = 150000 rows
//   size-6 cycles: 30000 cycles x 6 rows = 180000 rows
// d_out layout: [edge_out NE*64][out5 150000*64][out6 180000*64]
// cycle_out == d_out + NE*64 (contiguous concat(out5,out6)) -> no extra copy.

// One block = 128 threads handles C cycles (R = S*C rows) fully fused:
//   gather -> mlp2 (relu 128->128->64) -> per-cycle segment sum -> autobahn
//   -> cycle_mlp (relu 384->128, relu 128->128, 128->64) -> d_out
template<int S, int C>
__global__ __launch_bounds__(128)
void cycle_kernel(const float* __restrict__ edge_rep,
                  const float* __restrict__ cyc,
                  const int*   __restrict__ e2c,
                  const float* __restrict__ W1,  const float* __restrict__ b1,
                  const float* __restrict__ W2,  const float* __restrict__ b2,
                  const float* __restrict__ Wc1, const float* __restrict__ bc1,
                  const float* __restrict__ Wc2, const float* __restrict__ bc2,
                  const float* __restrict__ Wc3, const float* __restrict__ bc3,
                  const float* __restrict__ Wid, const float* __restrict__ Wsum,
                  const float* __restrict__ bab,
                  float* __restrict__ out,
                  int n_cyc)
{
    constexpr int R = S * C;           // rows per block (10 or 12)
    __shared__ float xin[R][128];      // mlp2 input [cyc | edge2cyc]; later reused for y2
    __shared__ float hbuf[R][128];     // mlp2 hidden; later reused for y1
    __shared__ float yin[R][384];      // [x | bsum | aut]

    const int tid  = threadIdx.x;
    const int d    = tid & 63;
    const int half = tid >> 6;         // wave id (0: tid<64, 1: tid>=64)
    const int base = blockIdx.x * (C * S);
    if (base + R > n_cyc * S) return;  // grids divide exactly for given sizes

    // ---- 1. gather & concat input: xin = [cyc_rep | edge_rep[i0]+edge_rep[i1]]
    for (int r = 0; r < R; ++r) {
        const int g = base + r;
        if (half == 0) {
            xin[r][d] = cyc[g * 64 + d];
        } else {
            const int i0 = e2c[2 * g];
            const int i1 = e2c[2 * g + 1];
            xin[r][64 + d] = edge_rep[i0 * 64 + d] + edge_rep[i1 * 64 + d];
        }
    }
    __syncthreads();

    // ---- 2. h = relu(xin @ W1 + b1)   (128 -> 128)
    {
        float acc[R];
        #pragma unroll
        for (int r = 0; r < R; ++r) acc[r] = 0.f;
        for (int k = 0; k < 128; k += 4) {
            const float w0 = W1[(k + 0) * 128 + tid];
            const float w1 = W1[(k + 1) * 128 + tid];
            const float w2 = W1[(k + 2) * 128 + tid];
            const float w3 = W1[(k + 3) * 128 + tid];
            #pragma unroll
            for (int r = 0; r < R; ++r) {
                const float4 xv = *(const float4*)&xin[r][k];
                acc[r] += xv.x * w0 + xv.y * w1 + xv.z * w2 + xv.w * w3;
            }
        }
        const float bb = b1[tid];
        #pragma unroll
        for (int r = 0; r < R; ++r) hbuf[r][tid] = fmaxf(acc[r] + bb, 0.f);
    }
    __syncthreads();

    // ---- 3. x = relu(h @ W2 + b2)  (128 -> 64), write to yin[:,0:64]
    {
        constexpr int RH = R / 2;
        float acc[RH];
        #pragma unroll
        for (int i = 0; i < RH; ++i) acc[i] = 0.f;
        const int r0 = half * RH;
        for (int k = 0; k < 128; k += 4) {
            const float w0 = W2[(k + 0) * 64 + d];
            const float w1 = W2[(k + 1) * 64 + d];
            const float w2 = W2[(k + 2) * 64 + d];
            const float w3 = W2[(k + 3) * 64 + d];
            #pragma unroll
            for (int i = 0; i < RH; ++i) {
                const float4 hv = *(const float4*)&hbuf[r0 + i][k];
                acc[i] += hv.x * w0 + hv.y * w1 + hv.z * w2 + hv.w * w3;
            }
        }
        const float bb = b2[d];
        #pragma unroll
        for (int i = 0; i < RH; ++i) yin[r0 + i][d] = fmaxf(acc[i] + bb, 0.f);
    }
    __syncthreads();

    // ---- 4. per-cycle sum broadcast back: yin[:,64:128] = bsum
    for (int cc = half; cc < C; cc += 2) {
        float s = 0.f;
        #pragma unroll
        for (int j = 0; j < S; ++j) s += yin[cc * S + j][d];
        #pragma unroll
        for (int j = 0; j < S; ++j) yin[cc * S + j][64 + d] = s;
    }
    __syncthreads();

    // ---- 5. autobahn: yin[:,128:384] = x @ Wid + bsum @ Wsum + bab  (64 -> 256)
    {
        float a0[R], a1[R];
        #pragma unroll
        for (int r = 0; r < R; ++r) { a0[r] = 0.f; a1[r] = 0.f; }
        for (int k = 0; k < 64; ++k) {
            const float wi0 = Wid[k * 256 + tid];
            const float wi1 = Wid[k * 256 + 128 + tid];
            const float ws0 = Wsum[k * 256 + tid];
            const float ws1 = Wsum[k * 256 + 128 + tid];
            #pragma unroll
            for (int r = 0; r < R; ++r) {
                const float xk = yin[r][k];
                const float sk = yin[r][64 + k];
                a0[r] += xk * wi0 + sk * ws0;
                a1[r] += xk * wi1 + sk * ws1;
            }
        }
        const float bb0 = bab[tid];
        const float bb1 = bab[128 + tid];
        #pragma unroll
        for (int r = 0; r < R; ++r) {
            yin[r][128 + tid] = a0[r] + bb0;
            yin[r][256 + tid] = a1[r] + bb1;
        }
    }
    __syncthreads();

    // ---- 6. y1 = relu(yin @ Wc1 + bc1)  (384 -> 128), into hbuf
    {
        float acc[R];
        #pragma unroll
        for (int r = 0; r < R; ++r) acc[r] = 0.f;
        for (int k = 0; k < 384; k += 4) {
            const float w0 = Wc1[(k + 0) * 128 + tid];
            const float w1 = Wc1[(k + 1) * 128 + tid];
            const float w2 = Wc1[(k + 2) * 128 + tid];
            const float w3 = Wc1[(k + 3) * 128 + tid];
            #pragma unroll
            for (int r = 0; r < R; ++r) {
                const float4 yv = *(const float4*)&yin[r][k];
                acc[r] += yv.x * w0 + yv.y * w1 + yv.z * w2 + yv.w * w3;
            }
        }
        const float bb = bc1[tid];
        #pragma unroll
        for (int r = 0; r < R; ++r) hbuf[r][tid] = fmaxf(acc[r] + bb, 0.f);
    }
    __syncthreads();

    // ---- 7. y2 = relu(y1 @ Wc2 + bc2)  (128 -> 128), into xin (reused)
    {
        float acc[R];
        #pragma unroll
        for (int r = 0; r < R; ++r) acc[r] = 0.f;
        for (int k = 0; k < 128; k += 4) {
            const float w0 = Wc2[(k + 0) * 128 + tid];
            const float w1 = Wc2[(k + 1) * 128 + tid];
            const float w2 = Wc2[(k + 2) * 128 + tid];
            const float w3 = Wc2[(k + 3) * 128 + tid];
            #pragma unroll
            for (int r = 0; r < R; ++r) {
                const float4 yv = *(const float4*)&hbuf[r][k];
                acc[r] += yv.x * w0 + yv.y * w1 + yv.z * w2 + yv.w * w3;
            }
        }
        const float bb = bc2[tid];
        #pragma unroll
        for (int r = 0; r < R; ++r) xin[r][tid] = fmaxf(acc[r] + bb, 0.f);
    }
    __syncthreads();

    // ---- 8. out = y2 @ Wc3 + bc3  (128 -> 64), straight to global
    {
        constexpr int RH = R / 2;
        float acc[RH];
        #pragma unroll
        for (int i = 0; i < RH; ++i) acc[i] = 0.f;
        const int r0 = half * RH;
        for (int k = 0; k < 128; k += 4) {
            const float w0 = Wc3[(k + 0) * 64 + d];
            const float w1 = Wc3[(k + 1) * 64 + d];
            const float w2 = Wc3[(k + 2) * 64 + d];
            const float w3 = Wc3[(k + 3) * 64 + d];
            #pragma unroll
            for (int i = 0; i < RH; ++i) {
                const float4 yv = *(const float4*)&xin[r0 + i][k];
                acc[i] += yv.x * w0 + yv.y * w1 + yv.z * w2 + yv.w * w3;
            }
        }
        const float bb = bc3[d];
        #pragma unroll
        for (int i = 0; i < RH; ++i) {
            const int g = base + r0 + i;
            out[g * 64 + d] = acc[i] + bb;
        }
    }
}

// One block = 128 threads handles R edges: gather 4 cycle_out rows + edge_rep,
// relu(128->128), (128->64) -> edge_out
template<int R>
__global__ __launch_bounds__(128)
void edge_kernel(const float* __restrict__ edge_rep,
                 const float* __restrict__ cycle_out,
                 const int*   __restrict__ c2e,
                 const float* __restrict__ We1, const float* __restrict__ be1,
                 const float* __restrict__ We2, const float* __restrict__ be2,
                 float* __restrict__ out, int ne)
{
    __shared__ float ein[R][128];
    __shared__ float hbuf[R][128];
    const int tid  = threadIdx.x;
    const int d    = tid & 63;
    const int half = tid >> 6;
    const int base = blockIdx.x * R;
    if (base + R > ne) return;   // NE divisible by R for given sizes

    for (int r = 0; r < R; ++r) {
        const int g = base + r;
        if (half == 0) {
            ein[r][d] = edge_rep[g * 64 + d];
        } else {
            const int i0 = c2e[g * 4 + 0];
            const int i1 = c2e[g * 4 + 1];
            const int i2 = c2e[g * 4 + 2];
            const int i3 = c2e[g * 4 + 3];
            ein[r][64 + d] = cycle_out[i0 * 64 + d] + cycle_out[i1 * 64 + d]
                           + cycle_out[i2 * 64 + d] + cycle_out[i3 * 64 + d];
        }
    }
    __syncthreads();

    {
        float acc[R];
        #pragma unroll
        for (int r = 0; r < R; ++r) acc[r] = 0.f;
        for (int k = 0; k < 128; k += 4) {
            const float w0 = We1[(k + 0) * 128 + tid];
            const float w1 = We1[(k + 1) * 128 + tid];
            const float w2 = We1[(k + 2) * 128 + tid];
            const float w3 = We1[(k + 3) * 128 + tid];
            #pragma unroll
            for (int r = 0; r < R; ++r) {
                const float4 xv = *(const float4*)&ein[r][k];
                acc[r] += xv.x * w0 + xv.y * w1 + xv.z * w2 + xv.w * w3;
            }
        }
        const float bb = be1[tid];
        #pragma unroll
        for (int r = 0; r < R; ++r) hbuf[r][tid] = fmaxf(acc[r] + bb, 0.f);
    }
    __syncthreads();

    {
        constexpr int RH = R / 2;
        float acc[RH];
        #pragma unroll
        for (int i = 0; i < RH; ++i) acc[i] = 0.f;
        const int r0 = half * RH;
        for (int k = 0; k < 128; k += 4) {
            const float w0 = We2[(k + 0) * 64 + d];
            const float w1 = We2[(k + 1) * 64 + d];
            const float w2 = We2[(k + 2) * 64 + d];
            const float w3 = We2[(k + 3) * 64 + d];
            #pragma unroll
            for (int i = 0; i < RH; ++i) {
                const float4 hv = *(const float4*)&hbuf[r0 + i][k];
                acc[i] += hv.x * w0 + hv.y * w1 + hv.z * w2 + hv.w * w3;
            }
        }
        const float bb = be2[d];
        #pragma unroll
        for (int i = 0; i < RH; ++i) out[(base + r0 + i) * 64 + d] = acc[i] + bb;
    }
}

extern "C" void kernel_launch(void* const* d_in, const int* in_sizes, int n_in,
                              void* d_out, int out_size, void* d_ws, size_t ws_size,
                              hipStream_t stream) {
    const float* edge_rep = (const float*)d_in[0];
    const float* cyc5     = (const float*)d_in[1];
    const float* cyc6     = (const float*)d_in[2];
    const int*   e2c5     = (const int*)  d_in[3];
    const int*   e2c6     = (const int*)  d_in[4];
    const int*   c2e      = (const int*)  d_in[5];
    const float* W1   = (const float*)d_in[6];
    const float* b1   = (const float*)d_in[7];
    const float* W2   = (const float*)d_in[8];
    const float* b2   = (const float*)d_in[9];
    const float* Wc1  = (const float*)d_in[10];
    const float* bc1  = (const float*)d_in[11];
    const float* Wc2  = (const float*)d_in[12];
    const float* bc2  = (const float*)d_in[13];
    const float* Wc3  = (const float*)d_in[14];
    const float* bc3  = (const float*)d_in[15];
    const float* We1  = (const float*)d_in[16];
    const float* be1  = (const float*)d_in[17];
    const float* We2  = (const float*)d_in[18];
    const float* be2  = (const float*)d_in[19];
    const float* Wid5 = (const float*)d_in[20];
    const float* Wsum5= (const float*)d_in[21];
    const float* bab5 = (const float*)d_in[22];
    const float* Wid6 = (const float*)d_in[23];
    const float* Wsum6= (const float*)d_in[24];
    const float* bab6 = (const float*)d_in[25];

    const int NE     = in_sizes[0] / 64;    // 200000
    const int nrows5 = in_sizes[1] / 64;    // 150000
    const int nrows6 = in_sizes[2] / 64;    // 180000
    const int n5c = nrows5 / 5;             // 30000
    const int n6c = nrows6 / 6;             // 30000

    float* out       = (float*)d_out;
    float* out_edge  = out;
    float* out5      = out + (size_t)NE * 64;
    float* out6      = out5 + (size_t)nrows5 * 64;
    const float* cycle_out = out5;          // contiguous concat(out5, out6)

    constexpr int C = 2;   // cycles per block
    cycle_kernel<5, C><<<n5c / C, 128, 0, stream>>>(
        edge_rep, cyc5, e2c5, W1, b1, W2, b2, Wc1, bc1, Wc2, bc2, Wc3, bc3,
        Wid5, Wsum5, bab5, out5, n5c);
    cycle_kernel<6, C><<<n6c / C, 128, 0, stream>>>(
        edge_rep, cyc6, e2c6, W1, b1, W2, b2, Wc1, bc1, Wc2, bc2, Wc3, bc3,
        Wid6, Wsum6, bab6, out6, n6c);

    constexpr int RE = 8;  // edges per block
    edge_kernel<RE><<<NE / RE, 128, 0, stream>>>(
        edge_rep, cycle_out, c2e, We1, be1, We2, be2, out_edge, NE);
}

// Round 3
// 550.333 us; speedup vs baseline: 4.6987x; 4.6987x over previous
//
#include <hip/hip_runtime.h>

// Edge_cycle fused block, bf16-MFMA version.
//   D=64, H=128. All GEMM layers have K=128 after the Autobahn collapse:
//   aut = linmap@[Wid;Wsum] + bab  (linear, not an output)  =>
//   y1 = relu(linmap @ Weff + beff),  Weff = Wc1[0:128] + [Wid;Wsum]@Wc1[128:384]
// Pipeline per cycle row: L1(128->128) L2(128->64) bsum L3=Weff(128->128)
//                         L4(128->128) L5(128->64 -> global)
// Edge: E1(128->128) E2(128->64 -> global)
// d_out layout: [edge_out NE*64][out5][out6]; cycle_out = d_out + NE*64.

#define LP 136   // LDS row pitch in bf16 units (128 + 8 pad -> 16B-aligned, 2-way-free banks)

typedef __attribute__((ext_vector_type(8))) short bhalf8;
typedef __attribute__((ext_vector_type(4))) float f32x4;

__device__ __forceinline__ unsigned short f2bf(float f) {
    unsigned u = __builtin_bit_cast(unsigned, f);
    u += 0x7fffu + ((u >> 16) & 1u);          // RNE
    return (unsigned short)(u >> 16);
}
__device__ __forceinline__ float bf2f(unsigned short s) {
    unsigned u = ((unsigned)s) << 16;
    return __builtin_bit_cast(float, u);
}
__device__ __forceinline__ void store4bf(unsigned short* p, float4 v) {
    uint2 u;
    u.x = (unsigned)f2bf(v.x) | ((unsigned)f2bf(v.y) << 16);
    u.y = (unsigned)f2bf(v.z) | ((unsigned)f2bf(v.w) << 16);
    *(uint2*)p = u;
}

// ---------------- prep kernels (run every launch; d_ws is re-poisoned) --------
// W [128 x N] fp32 row-major -> WT [N x 128] bf16
__global__ void tcast_kernel(const float* __restrict__ W, unsigned short* __restrict__ WT,
                             int logN) {
    int i = blockIdx.x * 256 + threadIdx.x;
    int k = i >> logN;
    int n = i & ((1 << logN) - 1);
    WT[n * 128 + k] = f2bf(W[i]);
}

// WeffT[n][k] = Wc1[k][n] + sum_j stk(k,j) * Wc1[128+j][n], stk = vstack(Wid, Wsum)
__global__ void weff_kernel(const float* __restrict__ Wc1, const float* __restrict__ Wid,
                            const float* __restrict__ Wsum, unsigned short* __restrict__ WeffT) {
    int k = blockIdx.x, n = threadIdx.x;
    const float* Ws = (k < 64) ? (Wid + (size_t)k * 256) : (Wsum + (size_t)(k - 64) * 256);
    float v = Wc1[k * 128 + n];
    for (int j = 0; j < 256; ++j) v = fmaf(Ws[j], Wc1[(128 + j) * 128 + n], v);
    WeffT[n * 128 + k] = f2bf(v);
}

// beff[n] = bc1[n] + sum_j bab[j] * Wc1[128+j][n]   (fp32)
__global__ void beff_kernel(const float* __restrict__ Wc1, const float* __restrict__ bc1,
                            const float* __restrict__ bab, float* __restrict__ beff) {
    int n = threadIdx.x;
    float v = bc1[n];
    for (int j = 0; j < 256; ++j) v = fmaf(bab[j], Wc1[(128 + j) * 128 + n], v);
    beff[n] = v;
}

// ---------------- MFMA building blocks ---------------------------------------
// copy 64 rows x 128 cols bf16 from WT into wbuf (pitch LP)
__device__ __forceinline__ void load_whalf(const unsigned short* __restrict__ WT,
                                           unsigned short* wbuf, int tid) {
    #pragma unroll
    for (int i = tid; i < 1024; i += 256) {
        int r = i >> 4, c = (i & 15) * 8;
        *(f32x4*)&wbuf[r * LP + c] = *(const f32x4*)&WT[r * 128 + c];
    }
}

// A fragments for all MT row-tiles, K=128 (4 chunks), kept in registers
template<int MT>
__device__ __forceinline__ void load_afr(const unsigned short* abuf, int m16, int q,
                                         bhalf8 (&afr)[MT][4]) {
    #pragma unroll
    for (int mt = 0; mt < MT; ++mt)
        #pragma unroll
        for (int kc = 0; kc < 4; ++kc)
            afr[mt][kc] = *(const bhalf8*)&abuf[(mt * 16 + m16) * LP + kc * 32 + q * 8];
}

template<int MT, bool RELU>
__device__ __forceinline__ void gemm_to_lds(const bhalf8 (&afr)[MT][4],
                                            const unsigned short* wbuf,
                                            const float* __restrict__ bias,
                                            int wrow0, int ntg,
                                            unsigned short* dbuf, int m16, int q) {
    bhalf8 bfr[4];
    #pragma unroll
    for (int kc = 0; kc < 4; ++kc)
        bfr[kc] = *(const bhalf8*)&wbuf[(wrow0 + m16) * LP + kc * 32 + q * 8];
    const float bb = bias[ntg * 16 + m16];
    #pragma unroll
    for (int mt = 0; mt < MT; ++mt) {
        f32x4 acc = {bb, bb, bb, bb};
        #pragma unroll
        for (int kc = 0; kc < 4; ++kc)
            acc = __builtin_amdgcn_mfma_f32_16x16x32_bf16(afr[mt][kc], bfr[kc], acc, 0, 0, 0);
        #pragma unroll
        for (int r = 0; r < 4; ++r) {
            float v = acc[r];
            if (RELU) v = fmaxf(v, 0.f);
            dbuf[(mt * 16 + q * 4 + r) * LP + ntg * 16 + m16] = f2bf(v);
        }
    }
}

template<int MT>
__device__ __forceinline__ void gemm_to_global(const bhalf8 (&afr)[MT][4],
                                               const unsigned short* wbuf,
                                               const float* __restrict__ bias,
                                               int wrow0, int ntg,
                                               float* __restrict__ out, int base,
                                               int m16, int q) {
    bhalf8 bfr[4];
    #pragma unroll
    for (int kc = 0; kc < 4; ++kc)
        bfr[kc] = *(const bhalf8*)&wbuf[(wrow0 + m16) * LP + kc * 32 + q * 8];
    const float bb = bias[ntg * 16 + m16];
    #pragma unroll
    for (int mt = 0; mt < MT; ++mt) {
        f32x4 acc = {bb, bb, bb, bb};
        #pragma unroll
        for (int kc = 0; kc < 4; ++kc)
            acc = __builtin_amdgcn_mfma_f32_16x16x32_bf16(afr[mt][kc], bfr[kc], acc, 0, 0, 0);
        #pragma unroll
        for (int r = 0; r < 4; ++r)
            out[(size_t)(base + mt * 16 + q * 4 + r) * 64 + ntg * 16 + m16] = acc[r];
    }
}

// K=128 -> N=128 layer, weights streamed in two 64-row halves; A-frags stay in regs
template<int MT, bool RELU>
__device__ __forceinline__ void layer128(const unsigned short* src, unsigned short* dst,
                                         const unsigned short* __restrict__ WT,
                                         const float* __restrict__ bias,
                                         unsigned short* wbuf,
                                         int tid, int m16, int q, int w, int wrow0) {
    load_whalf(WT, wbuf, tid);
    bhalf8 afr[MT][4];
    load_afr<MT>(src, m16, q, afr);
    __syncthreads();
    gemm_to_lds<MT, RELU>(afr, wbuf, bias, wrow0, w, dst, m16, q);
    __syncthreads();
    load_whalf(WT + 64 * 128, wbuf, tid);
    __syncthreads();
    gemm_to_lds<MT, RELU>(afr, wbuf, bias, wrow0, 4 + w, dst, m16, q);
    __syncthreads();
}

// K=128 -> N=64 layer into LDS cols 0:63
template<int MT, bool RELU>
__device__ __forceinline__ void layer64_lds(const unsigned short* src, unsigned short* dst,
                                            const unsigned short* __restrict__ WT,
                                            const float* __restrict__ bias,
                                            unsigned short* wbuf,
                                            int tid, int m16, int q, int w, int wrow0) {
    load_whalf(WT, wbuf, tid);
    bhalf8 afr[MT][4];
    load_afr<MT>(src, m16, q, afr);
    __syncthreads();
    gemm_to_lds<MT, RELU>(afr, wbuf, bias, wrow0, w, dst, m16, q);
    __syncthreads();
}

// K=128 -> N=64 layer straight to global fp32 (no relu)
template<int MT>
__device__ __forceinline__ void layer64_out(const unsigned short* src,
                                            const unsigned short* __restrict__ WT,
                                            const float* __restrict__ bias,
                                            unsigned short* wbuf,
                                            float* __restrict__ out, int base,
                                            int tid, int m16, int q, int w, int wrow0) {
    load_whalf(WT, wbuf, tid);
    bhalf8 afr[MT][4];
    load_afr<MT>(src, m16, q, afr);
    __syncthreads();
    gemm_to_global<MT>(afr, wbuf, bias, wrow0, w, out, base, m16, q);
}

// ---------------- main kernels -----------------------------------------------
template<int S, int C>
__global__ __launch_bounds__(256, 2)
void cycle_mfma(const float* __restrict__ edge_rep, const float* __restrict__ cyc,
                const int* __restrict__ e2c,
                const unsigned short* __restrict__ W1T, const float* __restrict__ b1,
                const unsigned short* __restrict__ W2T, const float* __restrict__ b2,
                const unsigned short* __restrict__ WeffT, const float* __restrict__ beff,
                const unsigned short* __restrict__ Wc2T, const float* __restrict__ bc2,
                const unsigned short* __restrict__ Wc3T, const float* __restrict__ bc3,
                float* __restrict__ out) {
    constexpr int R = S * C;
    constexpr int MT = R / 16;
    static_assert(R % 16 == 0, "rows per block must be multiple of 16");
    __shared__ unsigned short bufA[R * LP];
    __shared__ unsigned short bufB[R * LP];
    __shared__ unsigned short wbuf[64 * LP];

    const int tid = threadIdx.x;
    const int lane = tid & 63;
    const int w = tid >> 6;
    const int m16 = lane & 15;
    const int q = lane >> 4;
    const int wrow0 = w * 16;
    const int base = blockIdx.x * R;

    // gather: bufA = [cyc | edge_rep[i0]+edge_rep[i1]]  (bf16)
    {
        const float4* cyc4 = (const float4*)cyc + (size_t)base * 16;
        for (int i = tid; i < R * 16; i += 256) {
            int r = i >> 4, c = i & 15;
            store4bf(&bufA[r * LP + c * 4], cyc4[i]);
        }
        const float4* er4 = (const float4*)edge_rep;
        for (int i = tid; i < R * 16; i += 256) {
            int r = i >> 4, c = i & 15;
            int g = base + r;
            int i0 = e2c[2 * g], i1 = e2c[2 * g + 1];
            float4 a = er4[(size_t)i0 * 16 + c];
            float4 b = er4[(size_t)i1 * 16 + c];
            float4 s{a.x + b.x, a.y + b.y, a.z + b.z, a.w + b.w};
            store4bf(&bufA[r * LP + 64 + c * 4], s);
        }
    }
    __syncthreads();

    layer128<MT, true>(bufA, bufB, W1T, b1, wbuf, tid, m16, q, w, wrow0);     // h
    layer64_lds<MT, true>(bufB, bufA, W2T, b2, wbuf, tid, m16, q, w, wrow0);  // x -> cols 0:63

    // per-cycle segment sum broadcast into cols 64:127
    {
        int c = tid & 63, grp = tid >> 6;
        for (int cc = grp; cc < C; cc += 4) {
            float s = 0.f;
            #pragma unroll
            for (int j = 0; j < S; ++j) s += bf2f(bufA[(cc * S + j) * LP + c]);
            unsigned short sb = f2bf(s);
            #pragma unroll
            for (int j = 0; j < S; ++j) bufA[(cc * S + j) * LP + 64 + c] = sb;
        }
    }
    __syncthreads();

    layer128<MT, true>(bufA, bufB, WeffT, beff, wbuf, tid, m16, q, w, wrow0); // y1
    layer128<MT, true>(bufB, bufA, Wc2T, bc2, wbuf, tid, m16, q, w, wrow0);   // y2
    layer64_out<MT>(bufA, Wc3T, bc3, wbuf, out, base, tid, m16, q, w, wrow0); // out
}

template<int RB>
__global__ __launch_bounds__(256, 2)
void edge_mfma(const float* __restrict__ edge_rep, const float* __restrict__ cycle_out,
               const int* __restrict__ c2e,
               const unsigned short* __restrict__ We1T, const float* __restrict__ be1,
               const unsigned short* __restrict__ We2T, const float* __restrict__ be2,
               float* __restrict__ out) {
    constexpr int MT = RB / 16;
    __shared__ unsigned short bufA[RB * LP];
    __shared__ unsigned short bufB[RB * LP];
    __shared__ unsigned short wbuf[64 * LP];

    const int tid = threadIdx.x;
    const int lane = tid & 63;
    const int w = tid >> 6;
    const int m16 = lane & 15;
    const int q = lane >> 4;
    const int wrow0 = w * 16;
    const int base = blockIdx.x * RB;

    {
        const float4* er4 = (const float4*)edge_rep + (size_t)base * 16;
        for (int i = tid; i < RB * 16; i += 256) {
            int r = i >> 4, c = i & 15;
            store4bf(&bufA[r * LP + c * 4], er4[i]);
        }
        const float4* co4 = (const float4*)cycle_out;
        for (int i = tid; i < RB * 16; i += 256) {
            int r = i >> 4, c = i & 15;
            int g = base + r;
            int j0 = c2e[4 * g], j1 = c2e[4 * g + 1], j2 = c2e[4 * g + 2], j3 = c2e[4 * g + 3];
            float4 a = co4[(size_t)j0 * 16 + c];
            float4 b = co4[(size_t)j1 * 16 + c];
            float4 cc = co4[(size_t)j2 * 16 + c];
            float4 d = co4[(size_t)j3 * 16 + c];
            float4 s{a.x + b.x + cc.x + d.x, a.y + b.y + cc.y + d.y,
                     a.z + b.z + cc.z + d.z, a.w + b.w + cc.w + d.w};
            store4bf(&bufA[r * LP + 64 + c * 4], s);
        }
    }
    __syncthreads();

    layer128<MT, true>(bufA, bufB, We1T, be1, wbuf, tid, m16, q, w, wrow0);
    layer64_out<MT>(bufB, We2T, be2, wbuf, out, base, tid, m16, q, w, wrow0);
}

// ---------------- launch ------------------------------------------------------
extern "C" void kernel_launch(void* const* d_in, const int* in_sizes, int n_in,
                              void* d_out, int out_size, void* d_ws, size_t ws_size,
                              hipStream_t stream) {
    const float* edge_rep = (const float*)d_in[0];
    const float* cyc5     = (const float*)d_in[1];
    const float* cyc6     = (const float*)d_in[2];
    const int*   e2c5     = (const int*)  d_in[3];
    const int*   e2c6     = (const int*)  d_in[4];
    const int*   c2e      = (const int*)  d_in[5];
    const float* W1   = (const float*)d_in[6];
    const float* b1   = (const float*)d_in[7];
    const float* W2   = (const float*)d_in[8];
    const float* b2   = (const float*)d_in[9];
    const float* Wc1  = (const float*)d_in[10];
    const float* bc1  = (const float*)d_in[11];
    const float* Wc2  = (const float*)d_in[12];
    const float* bc2  = (const float*)d_in[13];
    const float* Wc3  = (const float*)d_in[14];
    const float* bc3  = (const float*)d_in[15];
    const float* We1  = (const float*)d_in[16];
    const float* be1  = (const float*)d_in[17];
    const float* We2  = (const float*)d_in[18];
    const float* be2  = (const float*)d_in[19];
    const float* Wid5 = (const float*)d_in[20];
    const float* Wsum5= (const float*)d_in[21];
    const float* bab5 = (const float*)d_in[22];
    const float* Wid6 = (const float*)d_in[23];
    const float* Wsum6= (const float*)d_in[24];
    const float* bab6 = (const float*)d_in[25];

    const int NE     = in_sizes[0] / 64;    // 200000
    const int nrows5 = in_sizes[1] / 64;    // 150000
    const int nrows6 = in_sizes[2] / 64;    // 180000
    const int n5c = nrows5 / 5;             // 30000
    const int n6c = nrows6 / 6;             // 30000

    // workspace layout (bf16 elements)
    unsigned short* wsp    = (unsigned short*)d_ws;
    unsigned short* W1T    = wsp;                 // 128x128
    unsigned short* W2T    = wsp + 16384;         // 64x128
    unsigned short* WeffT5 = wsp + 24576;         // 128x128
    unsigned short* WeffT6 = wsp + 40960;         // 128x128
    unsigned short* Wc2T   = wsp + 57344;         // 128x128
    unsigned short* Wc3T   = wsp + 73728;         // 64x128
    unsigned short* We1T   = wsp + 81920;         // 128x128
    unsigned short* We2T   = wsp + 98304;         // 64x128
    float* beff5 = (float*)(wsp + 106496);        // 128 fp32
    float* beff6 = (float*)(wsp + 106752);        // 128 fp32

    // prep: transpose+cast weights, fold Autobahn into Weff/beff
    tcast_kernel<<<64, 256, 0, stream>>>(W1,  W1T,  7);
    tcast_kernel<<<32, 256, 0, stream>>>(W2,  W2T,  6);
    tcast_kernel<<<64, 256, 0, stream>>>(Wc2, Wc2T, 7);
    tcast_kernel<<<32, 256, 0, stream>>>(Wc3, Wc3T, 6);
    tcast_kernel<<<64, 256, 0, stream>>>(We1, We1T, 7);
    tcast_kernel<<<32, 256, 0, stream>>>(We2, We2T, 6);
    weff_kernel<<<128, 128, 0, stream>>>(Wc1, Wid5, Wsum5, WeffT5);
    weff_kernel<<<128, 128, 0, stream>>>(Wc1, Wid6, Wsum6, WeffT6);
    beff_kernel<<<1, 128, 0, stream>>>(Wc1, bc1, bab5, beff5);
    beff_kernel<<<1, 128, 0, stream>>>(Wc1, bc1, bab6, beff6);

    float* out      = (float*)d_out;
    float* out5     = out + (size_t)NE * 64;
    float* out6     = out5 + (size_t)nrows5 * 64;
    const float* cycle_out = out5;

    cycle_mfma<5, 16><<<n5c / 16, 256, 0, stream>>>(
        edge_rep, cyc5, e2c5, W1T, b1, W2T, b2, WeffT5, beff5,
        Wc2T, bc2, Wc3T, bc3, out5);
    cycle_mfma<6, 8><<<n6c / 8, 256, 0, stream>>>(
        edge_rep, cyc6, e2c6, W1T, b1, W2T, b2, WeffT6, beff6,
        Wc2T, bc2, Wc3T, bc3, out6);
    edge_mfma<64><<<NE / 64, 256, 0, stream>>>(
        edge_rep, cycle_out, c2e, We1T, be1, We2T, be2, out);
}

// Round 4
// 448.860 us; speedup vs baseline: 5.7609x; 1.2261x over previous
//
#include <hip/hip_runtime.h>

// Edge_cycle fused block, bf16-MFMA, round 4.
//   Autobahn collapse: aut = linmap@[Wid;Wsum]+bab (linear, not an output) =>
//   y1 = relu(linmap @ Weff + beff), Weff = Wc1[0:128] + [Wid;Wsum]@Wc1[128:384].
//   All layers K=128. B-fragments are read DIRECTLY from global (L2-resident
//   128KB weight set) -- no LDS weight staging, no staging barriers.
//   Activations ping-pong bufA<->bufB: exactly one __syncthreads per layer.
// d_out layout: [edge_out NE*64][out5][out6]; cycle_out = d_out + NE*64.

#define LP 136   // LDS row pitch in bf16 units (128+8: 16B-aligned, 2-way-free banks)

typedef __attribute__((ext_vector_type(8))) short bhalf8;
typedef __attribute__((ext_vector_type(4))) float f32x4;

__device__ __forceinline__ unsigned short f2bf(float f) {
    unsigned u = __builtin_bit_cast(unsigned, f);
    u += 0x7fffu + ((u >> 16) & 1u);          // RNE
    return (unsigned short)(u >> 16);
}
__device__ __forceinline__ float bf2f(unsigned short s) {
    unsigned u = ((unsigned)s) << 16;
    return __builtin_bit_cast(float, u);
}
__device__ __forceinline__ void store4bf(unsigned short* p, float4 v) {
    uint2 u;
    u.x = (unsigned)f2bf(v.x) | ((unsigned)f2bf(v.y) << 16);
    u.y = (unsigned)f2bf(v.z) | ((unsigned)f2bf(v.w) << 16);
    *(uint2*)p = u;
}

// ---------------- prep kernels (2 launches total) -----------------------------
// blocks 0-63:W1  64-95:W2  96-159:Wc2  160-191:Wc3  192-255:We1  256-287:We2
__global__ void tcast_all(const float* __restrict__ W1,  const float* __restrict__ W2,
                          const float* __restrict__ Wc2, const float* __restrict__ Wc3,
                          const float* __restrict__ We1, const float* __restrict__ We2,
                          unsigned short* W1T, unsigned short* W2T,
                          unsigned short* Wc2T, unsigned short* Wc3T,
                          unsigned short* We1T, unsigned short* We2T) {
    int b = blockIdx.x;
    const float* W; unsigned short* WT; int logN, i0;
    if      (b < 64)  { W = W1;  WT = W1T;  logN = 7; i0 = b; }
    else if (b < 96)  { W = W2;  WT = W2T;  logN = 6; i0 = b - 64; }
    else if (b < 160) { W = Wc2; WT = Wc2T; logN = 7; i0 = b - 96; }
    else if (b < 192) { W = Wc3; WT = Wc3T; logN = 6; i0 = b - 160; }
    else if (b < 256) { W = We1; WT = We1T; logN = 7; i0 = b - 192; }
    else              { W = We2; WT = We2T; logN = 6; i0 = b - 256; }
    int i = i0 * 256 + threadIdx.x;
    int k = i >> logN;
    int n = i & ((1 << logN) - 1);
    WT[n * 128 + k] = f2bf(W[i]);
}

// blocks 0-127: WeffT5 row k=b; 128-255: WeffT6; 256: beff5; 257: beff6
__global__ void weff_all(const float* __restrict__ Wc1,
                         const float* __restrict__ Wid5, const float* __restrict__ Wsum5,
                         const float* __restrict__ Wid6, const float* __restrict__ Wsum6,
                         const float* __restrict__ bab5, const float* __restrict__ bab6,
                         const float* __restrict__ bc1,
                         unsigned short* WeffT5, unsigned short* WeffT6,
                         float* beff5, float* beff6) {
    int b = blockIdx.x, n = threadIdx.x;
    if (b < 256) {
        int k = b & 127;
        const float* Wid  = (b < 128) ? Wid5  : Wid6;
        const float* Wsum = (b < 128) ? Wsum5 : Wsum6;
        unsigned short* WT = (b < 128) ? WeffT5 : WeffT6;
        const float* Ws = (k < 64) ? (Wid + (size_t)k * 256) : (Wsum + (size_t)(k - 64) * 256);
        float v = Wc1[k * 128 + n];
        for (int j = 0; j < 256; ++j) v = fmaf(Ws[j], Wc1[(128 + j) * 128 + n], v);
        WT[n * 128 + k] = f2bf(v);
    } else {
        const float* bab = (b == 256) ? bab5 : bab6;
        float* beff = (b == 256) ? beff5 : beff6;
        float v = bc1[n];
        for (int j = 0; j < 256; ++j) v = fmaf(bab[j], Wc1[(128 + j) * 128 + n], v);
        beff[n] = v;
    }
}

// ---------------- MFMA layer: B direct from global, A from LDS ---------------
// G=2: N=128 (col groups w, w+4). G=1: N=64 (col group w).
template<int MT, bool RELU, int G>
__device__ __forceinline__ void layerG(const unsigned short* src, unsigned short* dst,
                                       const unsigned short* __restrict__ WT,
                                       const float* __restrict__ bias,
                                       int m16, int q, int w) {
    // B fragments straight from global (issued first to cover latency)
    bhalf8 bfr[G][4];
    #pragma unroll
    for (int g = 0; g < G; ++g) {
        const int ntg = w + g * 4;
        #pragma unroll
        for (int kc = 0; kc < 4; ++kc)
            bfr[g][kc] = *(const bhalf8*)&WT[(size_t)(ntg * 16 + m16) * 128 + kc * 32 + q * 8];
    }
    // A fragments from LDS
    bhalf8 afr[MT][4];
    #pragma unroll
    for (int mt = 0; mt < MT; ++mt)
        #pragma unroll
        for (int kc = 0; kc < 4; ++kc)
            afr[mt][kc] = *(const bhalf8*)&src[(mt * 16 + m16) * LP + kc * 32 + q * 8];
    #pragma unroll
    for (int g = 0; g < G; ++g) {
        const int ntg = w + g * 4;
        const float bb = bias[ntg * 16 + m16];
        #pragma unroll
        for (int mt = 0; mt < MT; ++mt) {
            f32x4 acc = {bb, bb, bb, bb};
            #pragma unroll
            for (int kc = 0; kc < 4; ++kc)
                acc = __builtin_amdgcn_mfma_f32_16x16x32_bf16(afr[mt][kc], bfr[g][kc], acc, 0, 0, 0);
            #pragma unroll
            for (int r = 0; r < 4; ++r) {
                float v = acc[r];
                if (RELU) v = fmaxf(v, 0.f);
                dst[(mt * 16 + q * 4 + r) * LP + ntg * 16 + m16] = f2bf(v);
            }
        }
    }
}

// N=64 final layer -> global fp32
template<int MT>
__device__ __forceinline__ void layer_out(const unsigned short* src,
                                          const unsigned short* __restrict__ WT,
                                          const float* __restrict__ bias,
                                          float* __restrict__ out, int base,
                                          int m16, int q, int w) {
    bhalf8 bfr[4];
    #pragma unroll
    for (int kc = 0; kc < 4; ++kc)
        bfr[kc] = *(const bhalf8*)&WT[(size_t)(w * 16 + m16) * 128 + kc * 32 + q * 8];
    bhalf8 afr[MT][4];
    #pragma unroll
    for (int mt = 0; mt < MT; ++mt)
        #pragma unroll
        for (int kc = 0; kc < 4; ++kc)
            afr[mt][kc] = *(const bhalf8*)&src[(mt * 16 + m16) * LP + kc * 32 + q * 8];
    const float bb = bias[w * 16 + m16];
    #pragma unroll
    for (int mt = 0; mt < MT; ++mt) {
        f32x4 acc = {bb, bb, bb, bb};
        #pragma unroll
        for (int kc = 0; kc < 4; ++kc)
            acc = __builtin_amdgcn_mfma_f32_16x16x32_bf16(afr[mt][kc], bfr[kc], acc, 0, 0, 0);
        #pragma unroll
        for (int r = 0; r < 4; ++r)
            out[(size_t)(base + mt * 16 + q * 4 + r) * 64 + w * 16 + m16] = acc[r];
    }
}

// ---------------- main kernels -----------------------------------------------
template<int S, int C, int MINW>
__global__ __launch_bounds__(256, MINW)
void cycle_mfma(const float* __restrict__ edge_rep, const float* __restrict__ cyc,
                const int* __restrict__ e2c,
                const unsigned short* __restrict__ W1T, const float* __restrict__ b1,
                const unsigned short* __restrict__ W2T, const float* __restrict__ b2,
                const unsigned short* __restrict__ WeffT, const float* __restrict__ beff,
                const unsigned short* __restrict__ Wc2T, const float* __restrict__ bc2,
                const unsigned short* __restrict__ Wc3T, const float* __restrict__ bc3,
                float* __restrict__ out) {
    constexpr int R = S * C;
    constexpr int MT = R / 16;
    static_assert(R % 16 == 0, "rows per block must be multiple of 16");
    __shared__ unsigned short bufA[R * LP];
    __shared__ unsigned short bufB[R * LP];

    const int tid = threadIdx.x;
    const int lane = tid & 63;
    const int w = tid >> 6;
    const int m16 = lane & 15;
    const int q = lane >> 4;
    const int base = blockIdx.x * R;

    // gather: bufA = [cyc | edge_rep[i0]+edge_rep[i1]]  (bf16)
    {
        const float4* cyc4 = (const float4*)cyc + (size_t)base * 16;
        for (int i = tid; i < R * 16; i += 256) {
            int r = i >> 4, c = i & 15;
            store4bf(&bufA[r * LP + c * 4], cyc4[i]);
        }
        const float4* er4 = (const float4*)edge_rep;
        for (int i = tid; i < R * 16; i += 256) {
            int r = i >> 4, c = i & 15;
            int g = base + r;
            int i0 = e2c[2 * g], i1 = e2c[2 * g + 1];
            float4 a = er4[(size_t)i0 * 16 + c];
            float4 b = er4[(size_t)i1 * 16 + c];
            float4 s{a.x + b.x, a.y + b.y, a.z + b.z, a.w + b.w};
            store4bf(&bufA[r * LP + 64 + c * 4], s);
        }
    }
    __syncthreads();

    layerG<MT, true, 2>(bufA, bufB, W1T, b1, m16, q, w);   // h = relu(in@W1)
    __syncthreads();
    layerG<MT, true, 1>(bufB, bufA, W2T, b2, m16, q, w);   // x -> bufA cols 0:63
    __syncthreads();

    // per-cycle segment sum broadcast into bufA cols 64:127
    {
        int c = tid & 63, grp = tid >> 6;
        for (int cc = grp; cc < C; cc += 4) {
            float s = 0.f;
            #pragma unroll
            for (int j = 0; j < S; ++j) s += bf2f(bufA[(cc * S + j) * LP + c]);
            unsigned short sb = f2bf(s);
            #pragma unroll
            for (int j = 0; j < S; ++j) bufA[(cc * S + j) * LP + 64 + c] = sb;
        }
    }
    __syncthreads();

    layerG<MT, true, 2>(bufA, bufB, WeffT, beff, m16, q, w); // y1
    __syncthreads();
    layerG<MT, true, 2>(bufB, bufA, Wc2T, bc2, m16, q, w);   // y2
    __syncthreads();
    layer_out<MT>(bufA, Wc3T, bc3, out, base, m16, q, w);    // out
}

template<int RB>
__global__ __launch_bounds__(256, 3)
void edge_mfma(const float* __restrict__ edge_rep, const float* __restrict__ cycle_out,
               const int* __restrict__ c2e,
               const unsigned short* __restrict__ We1T, const float* __restrict__ be1,
               const unsigned short* __restrict__ We2T, const float* __restrict__ be2,
               float* __restrict__ out) {
    constexpr int MT = RB / 16;
    __shared__ unsigned short bufA[RB * LP];
    __shared__ unsigned short bufB[RB * LP];

    const int tid = threadIdx.x;
    const int lane = tid & 63;
    const int w = tid >> 6;
    const int m16 = lane & 15;
    const int q = lane >> 4;
    const int base = blockIdx.x * RB;

    {
        const float4* er4 = (const float4*)edge_rep + (size_t)base * 16;
        for (int i = tid; i < RB * 16; i += 256) {
            int r = i >> 4, c = i & 15;
            store4bf(&bufA[r * LP + c * 4], er4[i]);
        }
        const float4* co4 = (const float4*)cycle_out;
        for (int i = tid; i < RB * 16; i += 256) {
            int r = i >> 4, c = i & 15;
            int g = base + r;
            int j0 = c2e[4 * g], j1 = c2e[4 * g + 1], j2 = c2e[4 * g + 2], j3 = c2e[4 * g + 3];
            float4 a = co4[(size_t)j0 * 16 + c];
            float4 b = co4[(size_t)j1 * 16 + c];
            float4 cc = co4[(size_t)j2 * 16 + c];
            float4 d = co4[(size_t)j3 * 16 + c];
            float4 s{a.x + b.x + cc.x + d.x, a.y + b.y + cc.y + d.y,
                     a.z + b.z + cc.z + d.z, a.w + b.w + cc.w + d.w};
            store4bf(&bufA[r * LP + 64 + c * 4], s);
        }
    }
    __syncthreads();

    layerG<MT, true, 2>(bufA, bufB, We1T, be1, m16, q, w);
    __syncthreads();
    layer_out<MT>(bufB, We2T, be2, out, base, m16, q, w);
}

// ---------------- launch ------------------------------------------------------
extern "C" void kernel_launch(void* const* d_in, const int* in_sizes, int n_in,
                              void* d_out, int out_size, void* d_ws, size_t ws_size,
                              hipStream_t stream) {
    const float* edge_rep = (const float*)d_in[0];
    const float* cyc5     = (const float*)d_in[1];
    const float* cyc6     = (const float*)d_in[2];
    const int*   e2c5     = (const int*)  d_in[3];
    const int*   e2c6     = (const int*)  d_in[4];
    const int*   c2e      = (const int*)  d_in[5];
    const float* W1   = (const float*)d_in[6];
    const float* b1   = (const float*)d_in[7];
    const float* W2   = (const float*)d_in[8];
    const float* b2   = (const float*)d_in[9];
    const float* Wc1  = (const float*)d_in[10];
    const float* bc1  = (const float*)d_in[11];
    const float* Wc2  = (const float*)d_in[12];
    const float* bc2  = (const float*)d_in[13];
    const float* Wc3  = (const float*)d_in[14];
    const float* bc3  = (const float*)d_in[15];
    const float* We1  = (const float*)d_in[16];
    const float* be1  = (const float*)d_in[17];
    const float* We2  = (const float*)d_in[18];
    const float* be2  = (const float*)d_in[19];
    const float* Wid5 = (const float*)d_in[20];
    const float* Wsum5= (const float*)d_in[21];
    const float* bab5 = (const float*)d_in[22];
    const float* Wid6 = (const float*)d_in[23];
    const float* Wsum6= (const float*)d_in[24];
    const float* bab6 = (const float*)d_in[25];

    const int NE     = in_sizes[0] / 64;    // 200000
    const int nrows5 = in_sizes[1] / 64;    // 150000
    const int nrows6 = in_sizes[2] / 64;    // 180000

    // workspace layout (bf16 elements)
    unsigned short* wsp    = (unsigned short*)d_ws;
    unsigned short* W1T    = wsp;                 // 128x128
    unsigned short* W2T    = wsp + 16384;         // 64x128
    unsigned short* WeffT5 = wsp + 24576;         // 128x128
    unsigned short* WeffT6 = wsp + 40960;         // 128x128
    unsigned short* Wc2T   = wsp + 57344;         // 128x128
    unsigned short* Wc3T   = wsp + 73728;         // 64x128
    unsigned short* We1T   = wsp + 81920;         // 128x128
    unsigned short* We2T   = wsp + 98304;         // 64x128
    float* beff5 = (float*)(wsp + 106496);        // 128 fp32
    float* beff6 = (float*)(wsp + 106752);        // 128 fp32

    tcast_all<<<288, 256, 0, stream>>>(W1, W2, Wc2, Wc3, We1, We2,
                                       W1T, W2T, Wc2T, Wc3T, We1T, We2T);
    weff_all<<<258, 128, 0, stream>>>(Wc1, Wid5, Wsum5, Wid6, Wsum6,
                                      bab5, bab6, bc1, WeffT5, WeffT6, beff5, beff6);

    float* out      = (float*)d_out;
    float* out5     = out + (size_t)NE * 64;
    float* out6     = out5 + (size_t)nrows5 * 64;
    const float* cycle_out = out5;

    cycle_mfma<5, 16, 3><<<nrows5 / 80, 256, 0, stream>>>(
        edge_rep, cyc5, e2c5, W1T, b1, W2T, b2, WeffT5, beff5,
        Wc2T, bc2, Wc3T, bc3, out5);
    cycle_mfma<6, 8, 4><<<nrows6 / 48, 256, 0, stream>>>(
        edge_rep, cyc6, e2c6, W1T, b1, W2T, b2, WeffT6, beff6,
        Wc2T, bc2, Wc3T, bc3, out6);
    edge_mfma<64><<<NE / 64, 256, 0, stream>>>(
        edge_rep, cycle_out, c2e, We1T, be1, We2T, be2, out);
}